// Round 1
// baseline (8050.842 us; speedup 1.0000x reference)
//
#include <hip/hip_runtime.h>
#include <cstdint>
#include <cstddef>

typedef __attribute__((ext_vector_type(8))) short short8;
typedef __attribute__((ext_vector_type(4))) float floatx4;
typedef unsigned short u16;

#define NSTEP 256

__device__ __forceinline__ unsigned f2b_rne(float x) {
  unsigned u = __builtin_bit_cast(unsigned, x);
  return (u + 0x7fffu + ((u >> 16) & 1u)) >> 16;
}
__device__ __forceinline__ float b2f(u16 b) {
  unsigned u = ((unsigned)b) << 16;
  return __builtin_bit_cast(float, u);
}
__device__ __forceinline__ float sigf(float x) {
  x = fminf(fmaxf(x, -30.f), 30.f);
  return __builtin_amdgcn_rcpf(1.f + __expf(-x));
}
__device__ __forceinline__ float tanhf_fast(float x) {
  x = fminf(fmaxf(x, -15.f), 15.f);
  float e = __expf(2.f * x);
  return (e - 1.f) * __builtin_amdgcn_rcpf(e + 1.f);
}

// ---------------- init: zero h rows t=0 and barrier counters ----------------
__global__ void init_kernel(u16* h0, u16* h1, unsigned* ctr) {
  int i = blockIdx.x * blockDim.x + threadIdx.x;
  if (i < 65536) { h0[i] = 0; h1[i] = 0; }
  if (i < 128) ctr[i] = 0;
}

// ---------------- fp32 -> bf16 cast (vectorized x4) ----------------
__global__ void cast_kernel(const float* __restrict__ in, u16* __restrict__ out, int n4) {
  int i = blockIdx.x * blockDim.x + threadIdx.x;
  int stride = gridDim.x * blockDim.x;
  for (; i < n4; i += stride) {
    float4 v = ((const float4*)in)[i];
    unsigned lo = f2b_rne(v.x) | (f2b_rne(v.y) << 16);
    unsigned hi = f2b_rne(v.z) | (f2b_rne(v.w) << 16);
    ((uint2*)out)[i] = make_uint2(lo, hi);
  }
}

// ---------------- big NT GEMM: C[16384][4096] bf16 = A[16384][1024] @ B[4096][1024]^T
// AL==0: A plain row-major [m][k].
// AL==1: A is blocked h-buffer: elem(m,k) at (m>>6)*65536 + (k>>4)*1024 + (m&63)*16 + (k&15)
template<int AL>
__global__ __launch_bounds__(256) void gemm_nt(
    const u16* __restrict__ A, const u16* __restrict__ B, u16* __restrict__ C) {
  __shared__ u16 As[128 * 32];
  __shared__ u16 Bs[128 * 32];
  const int bid = blockIdx.x;
  const int m_blk = (bid >> 5) << 7;
  const int n_blk = (bid & 31) << 7;
  const int tid = threadIdx.x;
  const int wv = tid >> 6, lane = tid & 63;
  const int q = lane >> 4, n16 = lane & 15;
  const int m0w = (wv >> 1) << 6, n0w = (wv & 1) << 6;

  const floatx4 vzero = {0.f, 0.f, 0.f, 0.f};
  floatx4 acc[4][4];
#pragma unroll
  for (int mt = 0; mt < 4; ++mt)
#pragma unroll
    for (int nt = 0; nt < 4; ++nt) acc[mt][nt] = vzero;

  for (int k0 = 0; k0 < 1024; k0 += 32) {
#pragma unroll
    for (int i = 0; i < 2; ++i) {
      int s = i * 256 + tid;           // slot 0..511
      int r = s >> 2, kk = (s & 3) << 3;
      int m = m_blk + r, k = k0 + kk;
      size_t a_off;
      if (AL == 0) a_off = (size_t)m * 1024 + k;
      else a_off = (size_t)(m >> 6) * 65536 + (size_t)(k >> 4) * 1024 + (size_t)(m & 63) * 16 + (k & 15);
      size_t b_off = (size_t)(n_blk + r) * 1024 + k;
      __builtin_amdgcn_global_load_lds(
          (const __attribute__((address_space(1))) unsigned int*)(A + a_off),
          (__attribute__((address_space(3))) unsigned int*)(As + (size_t)(i * 256 + wv * 64) * 8),
          16, 0, 0);
      __builtin_amdgcn_global_load_lds(
          (const __attribute__((address_space(1))) unsigned int*)(B + b_off),
          (__attribute__((address_space(3))) unsigned int*)(Bs + (size_t)(i * 256 + wv * 64) * 8),
          16, 0, 0);
    }
    __syncthreads();
    short8 af[4], bf[4];
#pragma unroll
    for (int mt = 0; mt < 4; ++mt)
      af[mt] = *(const short8*)(As + (m0w + mt * 16 + n16) * 32 + q * 8);
#pragma unroll
    for (int nt = 0; nt < 4; ++nt)
      bf[nt] = *(const short8*)(Bs + (n0w + nt * 16 + n16) * 32 + q * 8);
#pragma unroll
    for (int mt = 0; mt < 4; ++mt)
#pragma unroll
      for (int nt = 0; nt < 4; ++nt)
        acc[mt][nt] = __builtin_amdgcn_mfma_f32_16x16x32_bf16(af[mt], bf[nt], acc[mt][nt], 0, 0, 0);
    __syncthreads();
  }
#pragma unroll
  for (int mt = 0; mt < 4; ++mt)
#pragma unroll
    for (int nt = 0; nt < 4; ++nt)
#pragma unroll
      for (int r = 0; r < 4; ++r) {
        int m = m_blk + m0w + mt * 16 + q * 4 + r;
        int n = n_blk + n0w + nt * 16 + n16;
        C[(size_t)m * 4096 + n] = (u16)f2b_rne(acc[mt][nt][r]);
      }
}

// ---------------- persistent LSTM recurrence (one layer) ----------------
// 64 WGs x 256 threads. WG jb owns hidden units [jb*16, jb*16+16) for all 4 gates.
// Wave w holds Wh weights for K-quarter [w*256,(w+1)*256) in registers (128 VGPRs).
// Hbuf blocked: [t (0..256)][jb 0..63][b 0..63][16] bf16; row 0 pre-zeroed.
// Per-step grid sync: monotonic atomic counter (device scope) + spin.
template<int WRITE_OUT>
__global__ __launch_bounds__(256, 1) void lstm_rec(
    const u16* __restrict__ Whb,    // [4096][1024] bf16
    const u16* __restrict__ G,      // [16384][4096] bf16 (x@Wx^T, no bias)
    const float* __restrict__ bias, // [4096]
    u16* Hbuf,                      // blocked, read+write (no restrict!)
    float* __restrict__ outp,       // [256*64*1024] fp32 or unused
    float* __restrict__ hf,         // [64*1024] fp32
    float* __restrict__ cf,         // [64*1024] fp32
    unsigned* ctr) {
  __shared__ float red[4][12][256];
  const int tid = threadIdx.x;
  const int wv = tid >> 6;
  const int lane = tid & 63;
  const int q = lane >> 4;
  const int n16 = lane & 15;
  const int jb = blockIdx.x;
  const int j0 = jb << 4;
  const int jg = j0 + n16;
  const int kq0 = wv << 8;

  // one-time: weight fragments into registers
  short8 wf[4][8];
#pragma unroll
  for (int g = 0; g < 4; ++g)
#pragma unroll
    for (int c = 0; c < 8; ++c)
      wf[g][c] = *(const short8*)(Whb + (size_t)(g * 1024 + jg) * 1024 + kq0 + c * 32 + q * 8);

  float bs[4];
#pragma unroll
  for (int g = 0; g < 4; ++g) bs[g] = bias[g * 1024 + jg];

  float cst[4] = {0.f, 0.f, 0.f, 0.f};
  const floatx4 vzero = {0.f, 0.f, 0.f, 0.f};

  for (int t = 0; t < NSTEP; ++t) {
    const u16* hrow = Hbuf + (size_t)t * 65536;

    // prefetch G for this step's elementwise (own m-tile = wv) — independent of h
    float gf[4][4];
#pragma unroll
    for (int g = 0; g < 4; ++g)
#pragma unroll
      for (int r = 0; r < 4; ++r)
        gf[g][r] = b2f(G[(size_t)(t * 64 + wv * 16 + q * 4 + r) * 4096 + g * 1024 + jg]);

    floatx4 acc[4][4];
#pragma unroll
    for (int m = 0; m < 4; ++m)
#pragma unroll
      for (int g = 0; g < 4; ++g) acc[m][g] = vzero;

    // h @ Wh^T over this wave's K-quarter, all 4 m-tiles, all 4 gates
#pragma unroll
    for (int c = 0; c < 8; ++c) {
      int k = kq0 + c * 32 + q * 8;
      const u16* hbase = hrow + (size_t)(k >> 4) * 1024 + (k & 15);
      short8 a[4];
#pragma unroll
      for (int m = 0; m < 4; ++m)
        a[m] = *(const short8*)(hbase + (m * 16 + n16) * 16);
#pragma unroll
      for (int m = 0; m < 4; ++m)
#pragma unroll
        for (int g = 0; g < 4; ++g)
          acc[m][g] = __builtin_amdgcn_mfma_f32_16x16x32_bf16(a[m], wf[g][c], acc[m][g], 0, 0, 0);
    }

    // cross-wave K reduction via LDS; wave m owns tiles (m, g=0..3)
#pragma unroll
    for (int m = 0; m < 4; ++m) {
      if (m == wv) continue;
      int slot = (m - (m > wv ? 1 : 0)) * 4;
#pragma unroll
      for (int g = 0; g < 4; ++g)
        *(floatx4*)&red[wv][slot + g][lane * 4] = acc[m][g];
    }
    __syncthreads();
    floatx4 tot[4];
#pragma unroll
    for (int g = 0; g < 4; ++g) tot[g] = acc[wv][g];
#pragma unroll
    for (int w2 = 0; w2 < 4; ++w2) {
      if (w2 == wv) continue;
      int slot = (wv - (wv > w2 ? 1 : 0)) * 4;
#pragma unroll
      for (int g = 0; g < 4; ++g)
        tot[g] += *(const floatx4*)&red[w2][slot + g][lane * 4];
    }

    // elementwise gates + state update; write h (blocked bf16) and outputs
    u16* hnext = Hbuf + (size_t)(t + 1) * 65536 + (size_t)jb * 1024;
#pragma unroll
    for (int r = 0; r < 4; ++r) {
      float pi = tot[0][r] + gf[0][r] + bs[0];
      float pf = tot[1][r] + gf[1][r] + bs[1];
      float po = tot[2][r] + gf[2][r] + bs[2];
      float pc = tot[3][r] + gf[3][r] + bs[3];
      float cn = sigf(pf) * cst[r] + sigf(pi) * tanhf_fast(pc);
      float h = sigf(po) * tanhf_fast(cn);
      cst[r] = cn;
      int brow = wv * 16 + q * 4 + r;
      hnext[brow * 16 + n16] = (u16)f2b_rne(h);
      if (WRITE_OUT) outp[((size_t)t * 64 + brow) * 1024 + jg] = h;
      if (t == NSTEP - 1) {
        hf[brow * 1024 + jg] = h;
        cf[brow * 1024 + jg] = cn;
      }
    }

    __syncthreads();  // LDS reuse safety; compiler drains vmcnt before s_barrier
    if (tid == 0) {
      __threadfence();  // agent-scope release: flush h writes to coherence point
      __hip_atomic_fetch_add(ctr, 1u, __ATOMIC_RELEASE, __HIP_MEMORY_SCOPE_AGENT);
      unsigned target = 64u * (unsigned)(t + 1);
      int spins = 0;
      while (__hip_atomic_load(ctr, __ATOMIC_ACQUIRE, __HIP_MEMORY_SCOPE_AGENT) < target) {
        __builtin_amdgcn_s_sleep(2);
        if (++spins > (1 << 17)) break;  // liveness guard
      }
    }
    __syncthreads();
  }
}

// ---------------- launch ----------------
extern "C" void kernel_launch(void* const* d_in, const int* in_sizes, int n_in,
                              void* d_out, int out_size, void* d_ws, size_t ws_size,
                              hipStream_t stream) {
  const float* X  = (const float*)d_in[0];   // [256][64][1024]
  const float* Wx = (const float*)d_in[1];   // [2][4096][1024]
  const float* Wh = (const float*)d_in[2];   // [2][4096][1024]
  const float* b  = (const float*)d_in[3];   // [2][4096]
  float* out = (float*)d_out;

  char* ws = (char*)d_ws;
  u16* Xbf  = (u16*)(ws);                         // 33,554,432 B
  u16* Wxbf = (u16*)(ws + 33554432);              // 16,777,216 B
  u16* Whbf = (u16*)(ws + 50331648);              // 16,777,216 B
  u16* H0   = (u16*)(ws + 67108864);              // 33,685,504 B (257*65536*2)
  u16* H1   = (u16*)(ws + 100794368);             // 33,685,504 B
  u16* G    = (u16*)(ws + 134479872);             // 134,217,728 B
  unsigned* ctr = (unsigned*)(ws + 268697600);    // 256 B

  float* out_seq = out;                // 16,777,216 floats
  float* Hf = out + 16777216;          // 131,072 floats
  float* Cf = out + 16777216 + 131072; // 131,072 floats

  init_kernel<<<256, 256, 0, stream>>>(H0, H1, ctr);
  cast_kernel<<<2048, 256, 0, stream>>>(X, Xbf, 16777216 / 4);
  cast_kernel<<<2048, 256, 0, stream>>>(Wx, Wxbf, 8388608 / 4);
  cast_kernel<<<2048, 256, 0, stream>>>(Wh, Whbf, 8388608 / 4);

  // layer 0: G0 = X @ Wx0^T ; recurrence
  gemm_nt<0><<<4096, 256, 0, stream>>>(Xbf, Wxbf, G);
  lstm_rec<0><<<64, 256, 0, stream>>>(Whbf, G, b, H0, (float*)nullptr, Hf, Cf, ctr);

  // layer 1: G1 = H0(seq) @ Wx1^T ; recurrence (writes outputs)
  gemm_nt<1><<<4096, 256, 0, stream>>>(H0 + 65536, Wxbf + 4194304, G);
  lstm_rec<1><<<64, 256, 0, stream>>>(Whbf + 4194304, G, b + 4096, H1, out_seq,
                                      Hf + 65536, Cf + 65536, ctr + 64);
}

// Round 2
// 7698.194 us; speedup vs baseline: 1.0458x; 1.0458x over previous
//
#include <hip/hip_runtime.h>
#include <cstdint>
#include <cstddef>

typedef __attribute__((ext_vector_type(8))) short short8;
typedef __attribute__((ext_vector_type(4))) float floatx4;
typedef unsigned short u16;

#define NSTEP 256

__device__ __forceinline__ unsigned f2b_rne(float x) {
  unsigned u = __builtin_bit_cast(unsigned, x);
  return (u + 0x7fffu + ((u >> 16) & 1u)) >> 16;
}
__device__ __forceinline__ float b2f(u16 b) {
  unsigned u = ((unsigned)b) << 16;
  return __builtin_bit_cast(float, u);
}
__device__ __forceinline__ float sigf(float x) {
  x = fminf(fmaxf(x, -30.f), 30.f);
  return __builtin_amdgcn_rcpf(1.f + __expf(-x));
}
__device__ __forceinline__ float tanhf_fast(float x) {
  x = fminf(fmaxf(x, -15.f), 15.f);
  float e = __expf(2.f * x);
  return (e - 1.f) * __builtin_amdgcn_rcpf(e + 1.f);
}

// ---------------- init: zero h rows t=0 and barrier counters ----------------
__global__ void init_kernel(u16* h0, u16* h1, unsigned* ctr) {
  int i = blockIdx.x * blockDim.x + threadIdx.x;
  if (i < 65536) { h0[i] = 0; h1[i] = 0; }
  if (i < 128) ctr[i] = 0;
}

// ---------------- fp32 -> bf16 cast (vectorized x4) ----------------
__global__ void cast_kernel(const float* __restrict__ in, u16* __restrict__ out, int n4) {
  int i = blockIdx.x * blockDim.x + threadIdx.x;
  int stride = gridDim.x * blockDim.x;
  for (; i < n4; i += stride) {
    float4 v = ((const float4*)in)[i];
    unsigned lo = f2b_rne(v.x) | (f2b_rne(v.y) << 16);
    unsigned hi = f2b_rne(v.z) | (f2b_rne(v.w) << 16);
    ((uint2*)out)[i] = make_uint2(lo, hi);
  }
}

// ---------------- big NT GEMM: C[16384][4096] bf16 = A[16384][1024] @ B[4096][1024]^T
// AL==0: A plain row-major [m][k].
// AL==1: A is blocked h-buffer: elem(m,k) at (m>>6)*65536 + (k>>4)*1024 + (m&63)*16 + (k&15)
template<int AL>
__global__ __launch_bounds__(256) void gemm_nt(
    const u16* __restrict__ A, const u16* __restrict__ B, u16* __restrict__ C) {
  __shared__ u16 As[128 * 32];
  __shared__ u16 Bs[128 * 32];
  const int bid = blockIdx.x;
  const int m_blk = (bid >> 5) << 7;
  const int n_blk = (bid & 31) << 7;
  const int tid = threadIdx.x;
  const int wv = tid >> 6, lane = tid & 63;
  const int q = lane >> 4, n16 = lane & 15;
  const int m0w = (wv >> 1) << 6, n0w = (wv & 1) << 6;

  const floatx4 vzero = {0.f, 0.f, 0.f, 0.f};
  floatx4 acc[4][4];
#pragma unroll
  for (int mt = 0; mt < 4; ++mt)
#pragma unroll
    for (int nt = 0; nt < 4; ++nt) acc[mt][nt] = vzero;

  for (int k0 = 0; k0 < 1024; k0 += 32) {
#pragma unroll
    for (int i = 0; i < 2; ++i) {
      int s = i * 256 + tid;           // slot 0..511
      int r = s >> 2, kk = (s & 3) << 3;
      int m = m_blk + r, k = k0 + kk;
      size_t a_off;
      if (AL == 0) a_off = (size_t)m * 1024 + k;
      else a_off = (size_t)(m >> 6) * 65536 + (size_t)(k >> 4) * 1024 + (size_t)(m & 63) * 16 + (k & 15);
      size_t b_off = (size_t)(n_blk + r) * 1024 + k;
      __builtin_amdgcn_global_load_lds(
          (const __attribute__((address_space(1))) unsigned int*)(A + a_off),
          (__attribute__((address_space(3))) unsigned int*)(As + (size_t)(i * 256 + wv * 64) * 8),
          16, 0, 0);
      __builtin_amdgcn_global_load_lds(
          (const __attribute__((address_space(1))) unsigned int*)(B + b_off),
          (__attribute__((address_space(3))) unsigned int*)(Bs + (size_t)(i * 256 + wv * 64) * 8),
          16, 0, 0);
    }
    __syncthreads();
    short8 af[4], bf[4];
#pragma unroll
    for (int mt = 0; mt < 4; ++mt)
      af[mt] = *(const short8*)(As + (m0w + mt * 16 + n16) * 32 + q * 8);
#pragma unroll
    for (int nt = 0; nt < 4; ++nt)
      bf[nt] = *(const short8*)(Bs + (n0w + nt * 16 + n16) * 32 + q * 8);
#pragma unroll
    for (int mt = 0; mt < 4; ++mt)
#pragma unroll
      for (int nt = 0; nt < 4; ++nt)
        acc[mt][nt] = __builtin_amdgcn_mfma_f32_16x16x32_bf16(af[mt], bf[nt], acc[mt][nt], 0, 0, 0);
    __syncthreads();
  }
#pragma unroll
  for (int mt = 0; mt < 4; ++mt)
#pragma unroll
    for (int nt = 0; nt < 4; ++nt)
#pragma unroll
      for (int r = 0; r < 4; ++r) {
        int m = m_blk + m0w + mt * 16 + q * 4 + r;
        int n = n_blk + n0w + nt * 16 + n16;
        C[(size_t)m * 4096 + n] = (u16)f2b_rne(acc[mt][nt][r]);
      }
}

// ---------------- persistent LSTM recurrence (one layer) ----------------
// 64 WGs x 256 threads. WG jb owns hidden units [jb*16, jb*16+16) for all 4 gates.
// Wave w holds Wh weights for K-quarter [w*256,(w+1)*256) in registers (128 VGPRs).
// Hbuf blocked: [t (0..256)][jb 0..63][b 0..63][16] bf16; row 0 pre-zeroed.
// Per-step grid sync: monotonic atomic counter + spin.
// Barrier protocol (round 2): RELAXED spin polls (agent-scope atomics execute at
// the coherence point -> no per-poll cache maintenance), exactly ONE release
// fence (buffer_wbl2) before arrival and ONE acquire fence (buffer_inv) after
// the spin exits. Round 1 used ACQUIRE polls + __threadfence -> an L2
// invalidate per poll iteration = 14.8 us/step fence storm (WRITE_SIZE 1.15 GB).
template<int WRITE_OUT>
__global__ __launch_bounds__(256, 1) void lstm_rec(
    const u16* __restrict__ Whb,    // [4096][1024] bf16
    const u16* __restrict__ G,      // [16384][4096] bf16 (x@Wx^T, no bias)
    const float* __restrict__ bias, // [4096]
    u16* Hbuf,                      // blocked, read+write (no restrict!)
    float* __restrict__ outp,       // [256*64*1024] fp32 or unused
    float* __restrict__ hf,         // [64*1024] fp32
    float* __restrict__ cf,         // [64*1024] fp32
    unsigned* ctr) {
  __shared__ float red[4][12][256];
  const int tid = threadIdx.x;
  const int wv = tid >> 6;
  const int lane = tid & 63;
  const int q = lane >> 4;
  const int n16 = lane & 15;
  const int jb = blockIdx.x;
  const int j0 = jb << 4;
  const int jg = j0 + n16;
  const int kq0 = wv << 8;

  // one-time: weight fragments into registers
  short8 wf[4][8];
#pragma unroll
  for (int g = 0; g < 4; ++g)
#pragma unroll
    for (int c = 0; c < 8; ++c)
      wf[g][c] = *(const short8*)(Whb + (size_t)(g * 1024 + jg) * 1024 + kq0 + c * 32 + q * 8);

  float bs[4];
#pragma unroll
  for (int g = 0; g < 4; ++g) bs[g] = bias[g * 1024 + jg];

  float cst[4] = {0.f, 0.f, 0.f, 0.f};
  const floatx4 vzero = {0.f, 0.f, 0.f, 0.f};

  // preload G fragment for t=0 (into registers; survives L2 invalidates)
  float gf[4][4];
#pragma unroll
  for (int g = 0; g < 4; ++g)
#pragma unroll
    for (int r = 0; r < 4; ++r)
      gf[g][r] = b2f(G[(size_t)(0 * 64 + wv * 16 + q * 4 + r) * 4096 + g * 1024 + jg]);

  for (int t = 0; t < NSTEP; ++t) {
    const u16* hrow = Hbuf + (size_t)t * 65536;

    floatx4 acc[4][4];
#pragma unroll
    for (int m = 0; m < 4; ++m)
#pragma unroll
      for (int g = 0; g < 4; ++g) acc[m][g] = vzero;

    // h @ Wh^T over this wave's K-quarter, all 4 m-tiles, all 4 gates
#pragma unroll
    for (int c = 0; c < 8; ++c) {
      int k = kq0 + c * 32 + q * 8;
      const u16* hbase = hrow + (size_t)(k >> 4) * 1024 + (k & 15);
      short8 a[4];
#pragma unroll
      for (int m = 0; m < 4; ++m)
        a[m] = *(const short8*)(hbase + (m * 16 + n16) * 16);
#pragma unroll
      for (int m = 0; m < 4; ++m)
#pragma unroll
        for (int g = 0; g < 4; ++g)
          acc[m][g] = __builtin_amdgcn_mfma_f32_16x16x32_bf16(a[m], wf[g][c], acc[m][g], 0, 0, 0);
    }

    // cross-wave K reduction via LDS; wave m owns tiles (m, g=0..3)
#pragma unroll
    for (int m = 0; m < 4; ++m) {
      if (m == wv) continue;
      int slot = (m - (m > wv ? 1 : 0)) * 4;
#pragma unroll
      for (int g = 0; g < 4; ++g)
        *(floatx4*)&red[wv][slot + g][lane * 4] = acc[m][g];
    }
    __syncthreads();
    floatx4 tot[4];
#pragma unroll
    for (int g = 0; g < 4; ++g) tot[g] = acc[wv][g];
#pragma unroll
    for (int w2 = 0; w2 < 4; ++w2) {
      if (w2 == wv) continue;
      int slot = (wv - (wv > w2 ? 1 : 0)) * 4;
#pragma unroll
      for (int g = 0; g < 4; ++g)
        tot[g] += *(const floatx4*)&red[w2][slot + g][lane * 4];
    }

    // elementwise gates + state update; write h (blocked bf16) and outputs
    u16* hnext = Hbuf + (size_t)(t + 1) * 65536 + (size_t)jb * 1024;
#pragma unroll
    for (int r = 0; r < 4; ++r) {
      float pi = tot[0][r] + gf[0][r] + bs[0];
      float pf = tot[1][r] + gf[1][r] + bs[1];
      float po = tot[2][r] + gf[2][r] + bs[2];
      float pc = tot[3][r] + gf[3][r] + bs[3];
      float cn = sigf(pf) * cst[r] + sigf(pi) * tanhf_fast(pc);
      float h = sigf(po) * tanhf_fast(cn);
      cst[r] = cn;
      int brow = wv * 16 + q * 4 + r;
      hnext[brow * 16 + n16] = (u16)f2b_rne(h);
      if (WRITE_OUT) outp[((size_t)t * 64 + brow) * 1024 + jg] = h;
      if (t == NSTEP - 1) {
        hf[brow * 1024 + jg] = h;
        cf[brow * 1024 + jg] = cn;
      }
    }

    // prefetch G for step t+1 into registers BEFORE the barrier; the loads
    // complete at the barrier's vmcnt drain and are immune to the L2 inv.
    if (t + 1 < NSTEP) {
#pragma unroll
      for (int g = 0; g < 4; ++g)
#pragma unroll
        for (int r = 0; r < 4; ++r)
          gf[g][r] = b2f(G[(size_t)((t + 1) * 64 + wv * 16 + q * 4 + r) * 4096 + g * 1024 + jg]);
    }

    // __syncthreads drains each wave's vmcnt (h stores now in L2)
    __syncthreads();
    if (tid == 0) {
      // ONE release fence: buffer_wbl2 -> all dirty L2 lines (incl. other
      // waves' h stores) reach the coherence point before the arrival add.
      __builtin_amdgcn_fence(__ATOMIC_RELEASE, "agent");
      __hip_atomic_fetch_add(ctr, 1u, __ATOMIC_RELAXED, __HIP_MEMORY_SCOPE_AGENT);
      unsigned target = 64u * (unsigned)(t + 1);
      int spins = 0;
      // RELAXED polls: no cache maintenance per iteration.
      while (__hip_atomic_load(ctr, __ATOMIC_RELAXED, __HIP_MEMORY_SCOPE_AGENT) < target) {
        __builtin_amdgcn_s_sleep(2);
        if (++spins > (1 << 17)) break;  // liveness guard
      }
      // ONE acquire fence: invalidate stale L2 before reading h row t+1.
      __builtin_amdgcn_fence(__ATOMIC_ACQUIRE, "agent");
    }
    __syncthreads();
  }
}

// ---------------- launch ----------------
extern "C" void kernel_launch(void* const* d_in, const int* in_sizes, int n_in,
                              void* d_out, int out_size, void* d_ws, size_t ws_size,
                              hipStream_t stream) {
  const float* X  = (const float*)d_in[0];   // [256][64][1024]
  const float* Wx = (const float*)d_in[1];   // [2][4096][1024]
  const float* Wh = (const float*)d_in[2];   // [2][4096][1024]
  const float* b  = (const float*)d_in[3];   // [2][4096]
  float* out = (float*)d_out;

  char* ws = (char*)d_ws;
  u16* Xbf  = (u16*)(ws);                         // 33,554,432 B
  u16* Wxbf = (u16*)(ws + 33554432);              // 16,777,216 B
  u16* Whbf = (u16*)(ws + 50331648);              // 16,777,216 B
  u16* H0   = (u16*)(ws + 67108864);              // 33,685,504 B (257*65536*2)
  u16* H1   = (u16*)(ws + 100794368);             // 33,685,504 B
  u16* G    = (u16*)(ws + 134479872);             // 134,217,728 B
  unsigned* ctr = (unsigned*)(ws + 268697600);    // 256 B

  float* out_seq = out;                // 16,777,216 floats
  float* Hf = out + 16777216;          // 131,072 floats
  float* Cf = out + 16777216 + 131072; // 131,072 floats

  init_kernel<<<256, 256, 0, stream>>>(H0, H1, ctr);
  cast_kernel<<<2048, 256, 0, stream>>>(X, Xbf, 16777216 / 4);
  cast_kernel<<<2048, 256, 0, stream>>>(Wx, Wxbf, 8388608 / 4);
  cast_kernel<<<2048, 256, 0, stream>>>(Wh, Whbf, 8388608 / 4);

  // layer 0: G0 = X @ Wx0^T ; recurrence
  gemm_nt<0><<<4096, 256, 0, stream>>>(Xbf, Wxbf, G);
  lstm_rec<0><<<64, 256, 0, stream>>>(Whbf, G, b, H0, (float*)nullptr, Hf, Cf, ctr);

  // layer 1: G1 = H0(seq) @ Wx1^T ; recurrence (writes outputs)
  gemm_nt<1><<<4096, 256, 0, stream>>>(H0 + 65536, Wxbf + 4194304, G);
  lstm_rec<1><<<64, 256, 0, stream>>>(Whbf + 4194304, G, b + 4096, H1, out_seq,
                                      Hf + 65536, Cf + 65536, ctr + 64);
}